// Round 1
// 353.500 us; speedup vs baseline: 1.0347x; 1.0347x over previous
//
#include <hip/hip_runtime.h>
#include <hip/hip_bf16.h>
#include <cstddef>

// ---------------- problem constants ----------------
#define DMODEL  768
#define DINNER  1536
#define DSTATE  64
#define NH      24
#define HD      64
#define CONVD   1664      // DINNER + 2*DSTATE
#define DINPROJ 3224      // 2*DINNER + 2*DSTATE + NH
#define SEQ     4096
#define BSZ     2
#define NTOK    8192      // BSZ*SEQ
#define NCHUNK  64        // SEQ/64
#define EPSF    1e-5f
#define LP      72        // LDS pitch (shorts) for SSD kernels
#define BUFS    8192      // 128*64 shorts per GEMM LDS buffer (128^2 core)

typedef __attribute__((ext_vector_type(8))) short  short8;
typedef __attribute__((ext_vector_type(4))) float  f32x4;

// ---------------- helpers ----------------
__device__ __forceinline__ unsigned short f2bf(float f) {
  union { float f; unsigned int u; } v; v.f = f;
  unsigned int r = v.u + 0x7fffu + ((v.u >> 16) & 1u);   // RNE
  return (unsigned short)(r >> 16);
}
__device__ __forceinline__ float bf2f(unsigned short u) {
  union { unsigned int i; float f; } v; v.i = ((unsigned int)u) << 16; return v.f;
}
__device__ __forceinline__ unsigned long long pack4bf(float a, float b, float c, float d) {
  return (unsigned long long)(f2bf(a) | ((unsigned int)f2bf(b) << 16))
       | ((unsigned long long)(f2bf(c) | ((unsigned int)f2bf(d) << 16)) << 32);
}
__device__ __forceinline__ float sigm(float x) { return 1.f / (1.f + __expf(-x)); }

// async 16B global -> LDS (lane i of the wave lands at ldsbase + i*16)
__device__ __forceinline__ void gld16(const unsigned short* g, unsigned short* l) {
  __builtin_amdgcn_global_load_lds(
      (const __attribute__((address_space(1))) unsigned int*)g,
      (__attribute__((address_space(3))) unsigned int*)l, 16, 0, 0);
}

// XCD-aware tile remap for 2D grids: XCD (id&7) owns a contiguous 1/8 of m-tiles.
__device__ __forceinline__ void xcd_tiles(int& m0, int& n0) {
  const int nt = gridDim.x, mt = gridDim.y;
  const int id = blockIdx.y * nt + blockIdx.x;
  const int mper = mt >> 3;
  const int xcd = id & 7, within = id >> 3;
  m0 = (xcd * mper + (within % mper)) * 128;
  n0 = (within / mper) * 128;
}

// ---------------- LayerNorm -> bf16 ----------------
__global__ __launch_bounds__(256) void k_ln(const float* __restrict__ x,
    const float* __restrict__ w, const float* __restrict__ b,
    unsigned short* __restrict__ xn)
{
  __shared__ float red[4];
  const int row = blockIdx.x, tid = threadIdx.x;
  const float* xr = x + (size_t)row * DMODEL;
  float v[3]; float s = 0.f;
  #pragma unroll
  for (int q = 0; q < 3; q++) { v[q] = xr[q*256 + tid]; s += v[q]; }
  #pragma unroll
  for (int off = 32; off; off >>= 1) s += __shfl_down(s, off);
  if ((tid & 63) == 0) red[tid >> 6] = s;
  __syncthreads();
  const float mu = (red[0] + red[1] + red[2] + red[3]) * (1.f / DMODEL);
  __syncthreads();
  float s2 = 0.f;
  #pragma unroll
  for (int q = 0; q < 3; q++) { float d = v[q] - mu; s2 += d * d; }
  #pragma unroll
  for (int off = 32; off; off >>= 1) s2 += __shfl_down(s2, off);
  if ((tid & 63) == 0) red[tid >> 6] = s2;
  __syncthreads();
  const float rs = rsqrtf((red[0] + red[1] + red[2] + red[3]) * (1.f / DMODEL) + EPSF);
  unsigned short* xo = xn + (size_t)row * DMODEL;
  #pragma unroll
  for (int q = 0; q < 3; q++) {
    int col = q*256 + tid;
    xo[col] = f2bf((v[q] - mu) * rs * w[col] + b[col]);
  }
}

// ---------------- 4 weight transposes in one dispatch (z-indexed) ----------------
__global__ __launch_bounds__(256) void k_wtrans4(
    const float* __restrict__ W0, unsigned short* __restrict__ T0,
    const float* __restrict__ W1, unsigned short* __restrict__ T1,
    const float* __restrict__ W2, unsigned short* __restrict__ T2,
    const float* __restrict__ W3, unsigned short* __restrict__ T3)
{
  const float* W; unsigned short* T; int K, N;
  switch (blockIdx.z) {
    case 0:  W = W0; T = T0; K = 768;  N = 3224; break;
    case 1:  W = W1; T = T1; K = 768;  N = 768;  break;
    case 2:  W = W2; T = T2; K = 1536; N = 768;  break;
    default: W = W3; T = T3; K = 768;  N = 768;  break;
  }
  const int n0 = blockIdx.x * 32, k0 = blockIdx.y * 32;
  if (n0 >= N || k0 >= K) return;
  __shared__ float tile[32][33];
  const int tid = threadIdx.x;
  const int tx = tid & 31, ty = tid >> 5;           // 32 x 8
  #pragma unroll
  for (int r = 0; r < 4; r++) {
    int k = k0 + ty + 8*r;
    if (k < K && n0 + tx < N) tile[ty + 8*r][tx] = W[(size_t)k * N + n0 + tx];
  }
  __syncthreads();
  #pragma unroll
  for (int r = 0; r < 4; r++) {
    int n = n0 + ty + 8*r, k = k0 + tx;
    if (n < N && k < K) T[(size_t)n * K + k] = f2bf(tile[tx][ty + 8*r]);
  }
}

// ======== 128x128 GEMM core, BK=64, DOUBLE-BUFFERED (1 barrier/iter) =============
// Prefetch distance 1; LDS swizzle: slot j of row r holds k-granule j ^ (r&7).
// epi: 0 plain, 1 sigmoid(C+bias[n]), 2 C+bias[n]+resid[m][n], 3 C*gmul[m][n].
// Cb!=null -> bf16 out.
__device__ __forceinline__ void gemm_core(const unsigned short* __restrict__ A,
    const unsigned short* __restrict__ Bt, float* __restrict__ C,
    unsigned short* __restrict__ Cb,
    int M, int N, int K, int epi, const float* __restrict__ bias,
    const float* __restrict__ resid, const unsigned short* __restrict__ gmul,
    int m0, int n0,
    unsigned short* As, unsigned short* Bs)      // each 2*BUFS shorts
{
  const int tid = threadIdx.x;
  const int lane = tid & 63, w = tid >> 6;
  const int wm = (w >> 1) * 64, wn = (w & 1) * 64;
  const int l15 = lane & 15, lq = lane >> 4;
  const int sw = l15 & 7;                  // fragment-read swizzle
  f32x4 acc[4][4];
  #pragma unroll
  for (int i = 0; i < 4; i++)
    #pragma unroll
    for (int j = 0; j < 4; j++) acc[i][j] = (f32x4){0.f, 0.f, 0.f, 0.f};

  int rowg[4], gq[4], nrg[4];
  #pragma unroll
  for (int r = 0; r < 4; r++) {
    int gi = (r * 4 + w) * 64 + lane;
    rowg[r] = gi >> 3;
    gq[r] = (gi & 7) ^ (rowg[r] & 7);
    int nr = n0 + rowg[r]; if (nr >= N) nr = N - 1;   // clamp; masked in epilogue
    nrg[r] = nr;
  }

  // prologue: loads(0) -> buffer 0
  #pragma unroll
  for (int r = 0; r < 4; r++)
    gld16(A + (size_t)(m0 + rowg[r]) * K + gq[r] * 8, &As[(r * 4 + w) * 512]);
  #pragma unroll
  for (int r = 0; r < 4; r++)
    gld16(Bt + (size_t)nrg[r] * K + gq[r] * 8, &Bs[(r * 4 + w) * 512]);

  int p = 0;
  for (int k0 = 0; k0 < K; k0 += 64) {
    __syncthreads();                       // drains loads(k0); protects buf 1-p
    if (k0 + 64 < K) {
      const int pn = p ^ 1;
      #pragma unroll
      for (int r = 0; r < 4; r++)
        gld16(A + (size_t)(m0 + rowg[r]) * K + (k0 + 64) + gq[r] * 8,
              &As[pn * BUFS + (r * 4 + w) * 512]);
      #pragma unroll
      for (int r = 0; r < 4; r++)
        gld16(Bt + (size_t)nrg[r] * K + (k0 + 64) + gq[r] * 8,
              &Bs[pn * BUFS + (r * 4 + w) * 512]);
    }
    const unsigned short* Ab = As + p * BUFS;
    const unsigned short* Bb = Bs + p * BUFS;
    #pragma unroll
    for (int ks = 0; ks < 2; ks++) {
      short8 a8[4], b8[4];
      #pragma unroll
      for (int mi = 0; mi < 4; mi++)
        a8[mi] = *(const short8*)(&Ab[(wm + 16 * mi + l15) * 64 + ((lq + 4 * ks) ^ sw) * 8]);
      #pragma unroll
      for (int ni = 0; ni < 4; ni++)
        b8[ni] = *(const short8*)(&Bb[(wn + 16 * ni + l15) * 64 + ((lq + 4 * ks) ^ sw) * 8]);
      #pragma unroll
      for (int mi = 0; mi < 4; mi++)
        #pragma unroll
        for (int ni = 0; ni < 4; ni++)
          acc[mi][ni] = __builtin_amdgcn_mfma_f32_16x16x32_bf16(a8[mi], b8[ni], acc[mi][ni], 0, 0, 0);
    }
    p ^= 1;
  }
  #pragma unroll
  for (int mi = 0; mi < 4; mi++) {
    #pragma unroll
    for (int r = 0; r < 4; r++) {
      int row = m0 + wm + 16*mi + lq*4 + r;
      #pragma unroll
      for (int ni = 0; ni < 4; ni++) {
        int col = n0 + wn + 16*ni + l15;
        if (col < N) {
          float vv = acc[mi][ni][r];
          if (epi == 1)      vv = sigm(vv + bias[col]);
          else if (epi == 2) vv = vv + bias[col] + resid[(size_t)row * N + col];
          else if (epi == 3) vv = vv * bf2f(gmul[(size_t)row * N + col]);
          if (Cb) Cb[(size_t)row * N + col] = f2bf(vv);
          else    C [(size_t)row * N + col] = vv;
        }
      }
    }
  }
}

__global__ __launch_bounds__(256) void k_gemm(const unsigned short* __restrict__ A,
    const unsigned short* __restrict__ Bt, float* __restrict__ C,
    unsigned short* __restrict__ Cb,
    int M, int N, int K, int epi, const float* __restrict__ bias,
    const float* __restrict__ resid, const unsigned short* __restrict__ gmul)
{
  __shared__ alignas(16) unsigned short As[2 * BUFS];
  __shared__ alignas(16) unsigned short Bs[2 * BUFS];
  int m0, n0;
  xcd_tiles(m0, n0);
  gemm_core(A, Bt, C, Cb, M, N, K, epi, bias, resid, gmul, m0, n0, As, Bs);
}

// ================= 256x256 8-PHASE GEMM core (K=768 fixed) =======================
// 512 threads = 8 waves (2M x 4N). Per-wave C = 128x64 = acc[8][4] f32x4.
// LDS 128 KiB: A [2buf][256][64] bf16 (granule j of row r holds k-granule j^(r&7));
//              B [2buf][2ks][256][32] bf16 (granule j of row r holds j^((r>>1)&3)).
// MFMA operands SWAPPED: mfma(b,a) -> lane holds 4 consecutive COLUMNS -> 8B stores.
// Iteration = 2 K-tiles (even->buf0, odd->buf1), 8 phases = (mi-half x ks) x 2 tiles.
// Per-phase: {ds_read frags | issue stage | bar | 16 MFMA (setprio) | [vmcnt(6)] | bar}.
// Stage schedule (tile 2j+1='o', 2j+2='e', 2j+3='O'):
//   ph1: A-o-Y        ph2: B-e-k0      ph3: -    ph4: A-e-X + B-e-k1  [vmcnt(6)]
//   ph5: A-e-Y        ph6: B-O-k0      ph7: -    ph8: A-O-X + B-O-k1  [vmcnt(6)]
// Each vmcnt(6) retires exactly one K-tile's 4 half-tiles (8 loads); 3 half-tiles
// (6 loads) stay in flight across every wait. WAR: every stage targets a slot whose
// last ds_read was >=1 phase earlier (reader's lgkmcnt(0) precedes its 2nd barrier).
// Tail (j=5): stages of tiles >=12 are clamped to k=0 (junk, never read, L2-hot).

template<int MIB>
__device__ __forceinline__ void mfma16(f32x4 (&acc)[8][4], const short8 (&a_)[4],
                                       const short8 (&bK)[4]) {
  __builtin_amdgcn_s_setprio(1);
  #pragma unroll
  for (int mi = 0; mi < 4; mi++)
    #pragma unroll
    for (int ni = 0; ni < 4; ni++)
      acc[MIB + mi][ni] =
          __builtin_amdgcn_mfma_f32_16x16x32_bf16(bK[ni], a_[mi], acc[MIB + mi][ni], 0, 0, 0);
  __builtin_amdgcn_s_setprio(0);
}

__device__ __forceinline__ short8 lds8(const unsigned short* L, int off) {
  return *(const short8*)(&L[off]);
}

#define FENCE() asm volatile("" ::: "memory")
#define BARX() do { __builtin_amdgcn_sched_barrier(0); FENCE(); \
  __builtin_amdgcn_s_barrier(); FENCE(); __builtin_amdgcn_sched_barrier(0); } while (0)
#define VW6() asm volatile("s_waitcnt vmcnt(6)" ::: "memory")

#define PH_LDA(BUF, MIBASE, AOFF) do { \
  a_[0] = lds8(L, (BUF) + arow + ((MIBASE)+0)*1024 + (AOFF)); \
  a_[1] = lds8(L, (BUF) + arow + ((MIBASE)+1)*1024 + (AOFF)); \
  a_[2] = lds8(L, (BUF) + arow + ((MIBASE)+2)*1024 + (AOFF)); \
  a_[3] = lds8(L, (BUF) + arow + ((MIBASE)+3)*1024 + (AOFF)); } while (0)

#define PH_LDB(BUF, KS) do { \
  bK[0] = lds8(L, brow + (BUF) + (KS)*8192 + 0*512 + boff); \
  bK[1] = lds8(L, brow + (BUF) + (KS)*8192 + 1*512 + boff); \
  bK[2] = lds8(L, brow + (BUF) + (KS)*8192 + 2*512 + boff); \
  bK[3] = lds8(L, brow + (BUF) + (KS)*8192 + 3*512 + boff); } while (0)

__device__ __forceinline__ void gemm256(const unsigned short* __restrict__ A,
    const unsigned short* __restrict__ Bt, unsigned short* __restrict__ Cb,
    int N, int m0, int n0, int epi, const float* __restrict__ bias,
    unsigned short* L)
{
  const int K = 768;                       // 12 K-tiles, 6 iterations
  const int tid = threadIdx.x;
  const int lane = tid & 63, w = tid >> 6;
  const int wm2 = w >> 2, wn4 = w & 3;
  const int l15 = lane & 15, lq = lane >> 4;
  const int aoff0 = ((lq)     ^ (l15 & 7)) * 8;
  const int aoff1 = ((lq + 4) ^ (l15 & 7)) * 8;
  const int boff  = (lq ^ ((l15 >> 1) & 3)) * 8;
  const int arow = (wm2 * 128 + l15) * 64;                 // + (mi)*1024 + buf + aoff
  const int brow = 32768 + (wn4 * 64 + l15) * 32;          // + buf + ks*8192 + ni*512 + boff

  // staging sources (per-thread, constant)
  const int lr3 = lane >> 3, lr2 = lane >> 2;
  const int gqA = ((lane & 7) ^ lr3) * 8;
  const int gqB = ((lane & 3) ^ (lr3 & 3)) * 8;
  const unsigned short* sA0 = A + (size_t)(m0 + 8*w + lr3) * K + gqA;       // rows   8w..
  const unsigned short* sA1 = sA0 + (size_t)128 * K;                        // rows 128+8w
  const unsigned short* sA2 = sA0 + (size_t)64  * K;                        // rows  64+8w
  const unsigned short* sA3 = sA0 + (size_t)192 * K;                        // rows 192+8w
  int rb0 = n0 + 16*w + lr2;        if (rb0 > N - 1) rb0 = N - 1;
  int rb1 = n0 + 128 + 16*w + lr2;  if (rb1 > N - 1) rb1 = N - 1;
  const unsigned short* sB0 = Bt + (size_t)rb0 * K + gqB;
  const unsigned short* sB1 = Bt + (size_t)rb1 * K + gqB;

  // staging dests (shorts; + buf*16384, B also + ks*8192)
  const int dA0 = w*512, dA1 = (16+w)*512, dA2 = (8+w)*512, dA3 = (24+w)*512;
  const int dB0 = 32768 + w*512, dB1 = 32768 + (8+w)*512;

  f32x4 acc[8][4];
  #pragma unroll
  for (int i = 0; i < 8; i++)
    #pragma unroll
    for (int jj = 0; jj < 4; jj++) acc[i][jj] = (f32x4){0.f, 0.f, 0.f, 0.f};
  short8 bK[4];

  // ---- prologue: K0 full (8), then K1 {B-k0, A-X, B-k1} (6) ----
  gld16(sA0, &L[dA0]); gld16(sA1, &L[dA1]);                         // K0 A-X
  gld16(sA2, &L[dA2]); gld16(sA3, &L[dA3]);                         // K0 A-Y
  gld16(sB0, &L[dB0]); gld16(sB1, &L[dB1]);                         // K0 B-k0
  gld16(sB0 + 32, &L[dB0 + 8192]); gld16(sB1 + 32, &L[dB1 + 8192]); // K0 B-k1
  gld16(sB0 + 64, &L[dB0 + 16384]); gld16(sB1 + 64, &L[dB1 + 16384]);           // K1 B-k0
  gld16(sA0 + 64, &L[dA0 + 16384]); gld16(sA1 + 64, &L[dA1 + 16384]);           // K1 A-X
  gld16(sB0 + 96, &L[dB0 + 16384 + 8192]); gld16(sB1 + 96, &L[dB1 + 16384 + 8192]); // K1 B-k1
  VW6();                                   // retires K0's 8; K1's 6 stay in flight
  FENCE(); __builtin_amdgcn_s_barrier(); FENCE(); __builtin_amdgcn_sched_barrier(0);

  #pragma unroll 1
  for (int j = 0; j < 6; j++) {
    const int kO1 = (2*j + 1) * 64;
    const int kE  = (2*j + 2 < 12) ? (2*j + 2) * 64 : 0;
    const int kO3 = (2*j + 3 < 12) ? (2*j + 3) * 64 : 0;
    short8 a_[4];

    // phase 1: buf0, mi 0-3, ks0; load B-even-k0; stage A-odd-Y
    PH_LDA(0, 0, aoff0); PH_LDB(0, 0);
    gld16(sA2 + kO1, &L[dA2 + 16384]); gld16(sA3 + kO1, &L[dA3 + 16384]);
    BARX(); mfma16<0>(acc, a_, bK); BARX();
    // phase 2: buf0, mi 4-7, ks0; stage B-even'-k0
    PH_LDA(0, 4, aoff0);
    gld16(sB0 + kE, &L[dB0]); gld16(sB1 + kE, &L[dB1]);
    BARX(); mfma16<4>(acc, a_, bK); BARX();
    // phase 3: buf0, mi 0-3, ks1; load B-even-k1
    PH_LDA(0, 0, aoff1); PH_LDB(0, 1);
    BARX(); mfma16<0>(acc, a_, bK); BARX();
    // phase 4: buf0, mi 4-7, ks1; stage A-even'-X + B-even'-k1; WAIT
    PH_LDA(0, 4, aoff1);
    gld16(sA0 + kE, &L[dA0]); gld16(sA1 + kE, &L[dA1]);
    gld16(sB0 + kE + 32, &L[dB0 + 8192]); gld16(sB1 + kE + 32, &L[dB1 + 8192]);
    BARX(); mfma16<4>(acc, a_, bK);
    __builtin_amdgcn_sched_barrier(0); VW6(); BARX();
    // phase 5: buf1, mi 0-3, ks0; load B-odd-k0; stage A-even'-Y
    PH_LDA(16384, 0, aoff0); PH_LDB(16384, 0);
    gld16(sA2 + kE, &L[dA2]); gld16(sA3 + kE, &L[dA3]);
    BARX(); mfma16<0>(acc, a_, bK); BARX();
    // phase 6: buf1, mi 4-7, ks0; stage B-odd'-k0
    PH_LDA(16384, 4, aoff0);
    gld16(sB0 + kO3, &L[dB0 + 16384]); gld16(sB1 + kO3, &L[dB1 + 16384]);
    BARX(); mfma16<4>(acc, a_, bK); BARX();
    // phase 7: buf1, mi 0-3, ks1; load B-odd-k1
    PH_LDA(16384, 0, aoff1); PH_LDB(16384, 1);
    BARX(); mfma16<0>(acc, a_, bK); BARX();
    // phase 8: buf1, mi 4-7, ks1; stage A-odd'-X + B-odd'-k1; WAIT
    PH_LDA(16384, 4, aoff1);
    gld16(sA0 + kO3, &L[dA0 + 16384]); gld16(sA1 + kO3, &L[dA1 + 16384]);
    gld16(sB0 + kO3 + 32, &L[dB0 + 16384 + 8192]); gld16(sB1 + kO3 + 32, &L[dB1 + 16384 + 8192]);
    BARX(); mfma16<4>(acc, a_, bK);
    __builtin_amdgcn_sched_barrier(0); VW6(); BARX();
  }

  // drain junk prefetches before the workgroup can retire / LDS reuse
  asm volatile("s_waitcnt vmcnt(0)" ::: "memory");

  // ---- epilogue: lane holds cols (ncb+16ni .. +3) of row (mrow+16mi) ----
  const int mrow = m0 + wm2 * 128 + l15;
  const int ncb  = n0 + wn4 * 64 + 4 * lq;
  if (epi == 0) {
    #pragma unroll
    for (int mi = 0; mi < 8; mi++) {
      unsigned short* Crow = Cb + (size_t)(mrow + 16*mi) * N + ncb;
      #pragma unroll
      for (int ni = 0; ni < 4; ni++) {
        if (ncb + 16*ni < N) {
          f32x4 v = acc[mi][ni];
          *(unsigned long long*)(Crow + 16*ni) = pack4bf(v[0], v[1], v[2], v[3]);
        }
      }
    }
  } else {            // epi==1: sigmoid(C + bias[n]) (N=768, no masking needed)
    f32x4 bb[4];
    #pragma unroll
    for (int ni = 0; ni < 4; ni++) bb[ni] = *(const f32x4*)(bias + ncb + 16*ni);
    #pragma unroll
    for (int mi = 0; mi < 8; mi++) {
      unsigned short* Crow = Cb + (size_t)(mrow + 16*mi) * N + ncb;
      #pragma unroll
      for (int ni = 0; ni < 4; ni++) {
        f32x4 v = acc[mi][ni];
        *(unsigned long long*)(Crow + 16*ni) = pack4bf(
            sigm(v[0] + bb[ni][0]), sigm(v[1] + bb[ni][1]),
            sigm(v[2] + bb[ni][2]), sigm(v[3] + bb[ni][3]));
      }
    }
  }
}

// in_proj (32m x 13n tiles) + gate (32m x 3n) in ONE dispatch: 512 blocks, 1/CU,
// exactly 2 occupancy rounds. XCD (id&7) owns 4 contiguous m-tiles (A L2-local,
// 4 blocks share each B-tile panel on the same XCD).
__global__ __launch_bounds__(512, 2) void k_ipg256(
    const unsigned short* __restrict__ XN, const unsigned short* __restrict__ WIT,
    unsigned short* __restrict__ ZXb,
    const unsigned short* __restrict__ WGT, unsigned short* __restrict__ Gb,
    const float* __restrict__ gate_b)
{
  __shared__ alignas(16) unsigned short L[65536];   // 128 KiB
  const int id = blockIdx.x;
  const int xcd = id & 7, within = id >> 3;
  if (within < 52) {
    const int m0 = (xcd * 4 + (within & 3)) * 256;
    const int n0 = (within >> 2) * 256;
    gemm256(XN, WIT, ZXb, DINPROJ, m0, n0, 0, nullptr, L);
  } else {
    const int w2 = within - 52;
    const int m0 = (xcd * 4 + (w2 & 3)) * 256;
    const int n0 = (w2 >> 2) * 256;
    gemm256(XN, WGT, Gb, DMODEL, m0, n0, 1, gate_b, L);
  }
}

// ---------------- LDS-tiled causal conv1d (K=4) + SiLU ---------------------------
__global__ __launch_bounds__(256) void k_conv(const unsigned short* __restrict__ zx,
    const float* __restrict__ cw, const float* __restrict__ cb,
    unsigned short* __restrict__ out)
{
  __shared__ alignas(8) unsigned short tile[67][132];   // pitch 264 B
  const int tid = threadIdx.x;
  const int c0 = blockIdx.x * 128;          // 13 tiles x 128 = 1664 = CONVD
  const int tc = blockIdx.y;                // 128 token-chunks of 64
  const int t0 = tc * 64;
  const bool haloOK = (tc & 63) != 0;       // chunk 0 of each batch has no halo
  for (int i = tid; i < 67 * 16; i += 256) {
    int row = i >> 4, g = i & 15;
    unsigned long long v0 = 0, v1 = 0;
    if (row >= 3 || haloOK) {
      const unsigned short* p = zx + (size_t)(t0 - 3 + row) * DINPROJ + DINNER + c0 + g * 8;
      v0 = *(const unsigned long long*)p;
      v1 = *(const unsigned long long*)(p + 4);
    }
    *(unsigned long long*)(&tile[row][g * 8])     = v0;
    *(unsigned long long*)(&tile[row][g * 8 + 4]) = v1;
  }
  __syncthreads();
  const int ch0 = (tid & 63) * 2;           // 0..126
  const int trow = tid >> 6;                // 0..3
  const int cg = c0 + ch0;
  float cw0[4], cw1[4];
  #pragma unroll
  for (int k = 0; k < 4; k++) { cw0[k] = cw[cg * 4 + k]; cw1[k] = cw[(cg + 1) * 4 + k]; }
  const float cb0 = cb[cg], cb1 = cb[cg + 1];
  #pragma unroll
  for (int q = 0; q < 16; q++) {
    int tq = trow * 16 + q;
    float a0 = cb0, a1 = cb1;
    #pragma unroll
    for (int k = 0; k < 4; k++) {
      unsigned int u = *(const unsigned int*)(&tile[tq + k][ch0]);
      a0 += bf2f((unsigned short)u) * cw0[k];
      a1 += bf2f((unsigned short)(u >> 16)) * cw1[k];
    }
    float s0 = a0 * sigm(a0), s1 = a1 * sigm(a1);
    *(unsigned int*)(out + (size_t)(t0 + tq) * CONVD + cg) =
        (unsigned int)f2bf(s0) | ((unsigned int)f2bf(s1) << 16);
  }
}

// ---------------- SSD pass 1 (MFMA): S[bh,c][n][p] (bf16) ------------------------
__global__ __launch_bounds__(256) void k_chunkstate(const unsigned short* __restrict__ zx,
    const unsigned short* __restrict__ xbcc, const float* __restrict__ dt_bias,
    const float* __restrict__ A_log, unsigned short* __restrict__ S, float* __restrict__ CD)
{
  const int c = blockIdx.x, bh = blockIdx.y;
  const int b = bh / NH, h = bh % NH;
  const int tid = threadIdx.x;
  const int lane = tid & 63, w = tid >> 6;
  const int l15 = lane & 15, lq = lane >> 4;
  __shared__ float wv_[64];
  __shared__ alignas(16) unsigned short Bwt[64][LP];  // [n][s]
  __shared__ alignas(16) unsigned short Xt [64][LP];  // [p][s]

  if (tid < 64) {                     // wave 0: dt, prefix-scan of Lc
    int t = c * 64 + tid;
    float xx = bf2f(zx[((size_t)(b * SEQ + t)) * DINPROJ + (DINNER + CONVD) + h]) + dt_bias[h];
    float dt_ = (xx > 15.f) ? xx : log1pf(__expf(xx));
    float Ah = -__expf(A_log[h]);
    float v = dt_ * Ah;
    #pragma unroll
    for (int off = 1; off < 64; off <<= 1) {
      float u = __shfl_up(v, off);
      if (tid >= off) v += u;
    }
    float L63 = __shfl(v, 63);
    wv_[tid] = __expf(L63 - v) * dt_;
    if (tid == 63) CD[bh * 64 + c] = __expf(v);
  }
  unsigned long long braw[4];
  #pragma unroll
  for (int it = 0; it < 4; it++) {
    int i4 = tid + 256 * it;
    int s = i4 >> 4, q4 = (i4 & 15) * 4;
    size_t rb = ((size_t)(b * SEQ) + c * 64 + s) * CONVD;
    braw[it] = *(const unsigned long long*)(xbcc + rb + DINNER + q4);
    unsigned short xs[4];
    *(unsigned long long*)xs = *(const unsigned long long*)(xbcc + rb + h * HD + q4);
    Xt[q4+0][s] = xs[0]; Xt[q4+1][s] = xs[1]; Xt[q4+2][s] = xs[2]; Xt[q4+3][s] = xs[3];
  }
  __syncthreads();
  #pragma unroll
  for (int it = 0; it < 4; it++) {
    int i4 = tid + 256 * it;
    int s = i4 >> 4, q4 = (i4 & 15) * 4;
    float wsc = wv_[s];
    unsigned short us[4];
    *(unsigned long long*)us = braw[it];
    Bwt[q4+0][s] = f2bf(bf2f(us[0]) * wsc);
    Bwt[q4+1][s] = f2bf(bf2f(us[1]) * wsc);
    Bwt[q4+2][s] = f2bf(bf2f(us[2]) * wsc);
    Bwt[q4+3][s] = f2bf(bf2f(us[3]) * wsc);
  }
  __syncthreads();
  const int n0 = 16 * w;
  short8 a0 = *(const short8*)(&Bwt[n0 + l15][lq * 8]);
  short8 a1 = *(const short8*)(&Bwt[n0 + l15][32 + lq * 8]);
  size_t sb = ((size_t)bh * 64 + c) * 4096;
  #pragma unroll
  for (int pt = 0; pt < 4; pt++) {
    f32x4 acc = (f32x4){0.f, 0.f, 0.f, 0.f};
    short8 b0 = *(const short8*)(&Xt[16*pt + l15][lq * 8]);
    short8 b1 = *(const short8*)(&Xt[16*pt + l15][32 + lq * 8]);
    acc = __builtin_amdgcn_mfma_f32_16x16x32_bf16(a0, b0, acc, 0, 0, 0);
    acc = __builtin_amdgcn_mfma_f32_16x16x32_bf16(a1, b1, acc, 0, 0, 0);
    #pragma unroll
    for (int r = 0; r < 4; r++) {
      int n = n0 + 4*lq + r, p = 16*pt + l15;
      S[sb + (size_t)n * 64 + p] = f2bf(acc[r]);
    }
  }
}

// ---------------- SSD pass 2: chunk recurrence (bf16 S, fp32 reg accumulator) ----
__global__ __launch_bounds__(256) void k_chunkrec(unsigned short* __restrict__ S,
    const float* __restrict__ CD)
{
  const int bh = blockIdx.x >> 4, part = blockIdx.x & 15;
  const int e = part * 256 + threadIdx.x;
  float g = 0.f;
  size_t base = (size_t)bh * 64 * 4096 + e;
  for (int c = 0; c < 64; c++) {
    size_t ad = base + (size_t)c * 4096;
    float sv = bf2f(S[ad]);
    float pc = CD[bh * 64 + c];
    S[ad] = f2bf(g);         // slot c now holds G_c (state before chunk c)
    g = pc * g + sv;
  }
}

// ---------------- SSD pass 3 (MFMA): per-chunk outputs (bf16 Y out) --------------
__global__ __launch_bounds__(256) void k_chunkout(const unsigned short* __restrict__ zx,
    const unsigned short* __restrict__ xbcc, const unsigned short* __restrict__ S,
    const float* __restrict__ dt_bias, const float* __restrict__ A_log,
    const float* __restrict__ Dp, unsigned short* __restrict__ Y)
{
  const int c = blockIdx.x, bh = blockIdx.y;
  const int b = bh / NH, h = bh % NH;
  const int tid = threadIdx.x;
  const int lane = tid & 63, w = tid >> 6;
  const int l15 = lane & 15, lq = lane >> 4;
  __shared__ float dts[64], Lc[64], ein[64];
  __shared__ alignas(16) unsigned short Cs  [64][LP];  // [i][n]
  __shared__ alignas(16) unsigned short BsPs[64][LP];  // [s][n], then P[i][s]
  __shared__ alignas(16) unsigned short Xt  [64][LP];  // [p][s]
  __shared__ alignas(16) unsigned short Gt  [64][LP];  // [p][n]

  if (tid < 64) {                     // wave 0: dt, prefix-scan of Lc
    int t = c * 64 + tid;
    float xx = bf2f(zx[((size_t)(b * SEQ + t)) * DINPROJ + (DINNER + CONVD) + h]) + dt_bias[h];
    float dt_ = (xx > 15.f) ? xx : log1pf(__expf(xx));
    dts[tid] = dt_;
    float Ah = -__expf(A_log[h]);
    float v = dt_ * Ah;
    #pragma unroll
    for (int off = 1; off < 64; off <<= 1) {
      float u = __shfl_up(v, off);
      if (tid >= off) v += u;
    }
    Lc[tid] = v;
    ein[tid] = __expf(v);
  }
  const size_t gslot = ((size_t)bh * 64 + c) * 4096;
  #pragma unroll
  for (int it = 0; it < 4; it++) {
    int i4 = tid + 256 * it;
    int rr = i4 >> 4, q4 = (i4 & 15) * 4;
    size_t rb = ((size_t)(b * SEQ) + c * 64 + rr) * CONVD;
    const unsigned short* pC = xbcc + rb + (DINNER + DSTATE) + q4;
    Cs[rr][q4+0] = pC[0]; Cs[rr][q4+1] = pC[1]; Cs[rr][q4+2] = pC[2]; Cs[rr][q4+3] = pC[3];
    const unsigned short* pB = xbcc + rb + DINNER + q4;
    BsPs[rr][q4+0] = pB[0]; BsPs[rr][q4+1] = pB[1]; BsPs[rr][q4+2] = pB[2]; BsPs[rr][q4+3] = pB[3];
    unsigned short xs[4];
    *(unsigned long long*)xs = *(const unsigned long long*)(xbcc + rb + h * HD + q4);
    Xt[q4+0][rr] = xs[0]; Xt[q4+1][rr] = xs[1]; Xt[q4+2][rr] = xs[2]; Xt[q4+3][rr] = xs[3];
    unsigned short gs[4];
    *(unsigned long long*)gs = *(const unsigned long long*)(S + gslot + (size_t)i4 * 4);
    Gt[q4+0][rr] = gs[0]; Gt[q4+1][rr] = gs[1]; Gt[q4+2][rr] = gs[2]; Gt[q4+3][rr] = gs[3];
  }
  __syncthreads();
  // ---- matmul1: G[i][s] = sum_n C[i][n] B[s][n]; apply causal decay mask -> P ----
  const int i0 = 16 * w;
  short8 ac0 = *(const short8*)(&Cs[i0 + l15][lq * 8]);
  short8 ac1 = *(const short8*)(&Cs[i0 + l15][32 + lq * 8]);
  float pp[4][4];
  #pragma unroll
  for (int st = 0; st < 4; st++) {
    f32x4 g = (f32x4){0.f, 0.f, 0.f, 0.f};
    if (st <= w) {                                   // wave-uniform causal skip
      short8 b0 = *(const short8*)(&BsPs[16*st + l15][lq * 8]);
      short8 b1 = *(const short8*)(&BsPs[16*st + l15][32 + lq * 8]);
      g = __builtin_amdgcn_mfma_f32_16x16x32_bf16(ac0, b0, g, 0, 0, 0);
      g = __builtin_amdgcn_mfma_f32_16x16x32_bf16(ac1, b1, g, 0, 0, 0);
    }
    #pragma unroll
    for (int r = 0; r < 4; r++) {
      int i = i0 + 4*lq + r, s = 16*st + l15;
      pp[st][r] = (s <= i) ? g[r] * __expf(Lc[i] - Lc[s]) * dts[s] : 0.f;
    }
  }
  __syncthreads();                                   // all waves done reading Bs
  #pragma unroll
  for (int st = 0; st < 4; st++)
    #pragma unroll
    for (int r = 0; r < 4; r++)
      BsPs[i0 + 4*lq + r][16*st + l15] = f2bf(pp[st][r]);   // P[i][s], s contiguous
  __syncthreads();
  // ---- matmul2+3: Y[i][p] = P@X + ein[i]*(C@G) + D*x ----
  short8 ap0 = *(const short8*)(&BsPs[i0 + l15][lq * 8]);
  short8 ap1 = *(const short8*)(&BsPs[i0 + l15][32 + lq * 8]);
  const float Dh = Dp[h];
  #pragma unroll
  for (int pt = 0; pt < 4; pt++) {
    const int p0 = 16 * pt;
    f32x4 y1 = (f32x4){0.f, 0.f, 0.f, 0.f};
    f32x4 y2 = (f32x4){0.f, 0.f, 0.f, 0.f};
    short8 bx0 = *(const short8*)(&Xt[p0 + l15][lq * 8]);
    y1 = __builtin_amdgcn_mfma_f32_16x16x32_bf16(ap0, bx0, y1, 0, 0, 0);
    if (w >= 2) {                                    // P rows of wave w have k < 16(w+1)
      short8 bx1 = *(const short8*)(&Xt[p0 + l15][32 + lq * 8]);
      y1 = __builtin_amdgcn_mfma_f32_16x16x32_bf16(ap1, bx1, y1, 0, 0, 0);
    }
    short8 bg0 = *(const short8*)(&Gt[p0 + l15][lq * 8]);
    short8 bg1 = *(const short8*)(&Gt[p0 + l15][32 + lq * 8]);
    y2 = __builtin_amdgcn_mfma_f32_16x16x32_bf16(ac0, bg0, y2, 0, 0, 0);
    y2 = __builtin_amdgcn_mfma_f32_16x16x32_bf16(ac1, bg1, y2, 0, 0, 0);
    #pragma unroll
    for (int r = 0; r < 4; r++) {
      int i = i0 + 4*lq + r, p = p0 + l15;
      float xv = bf2f(Xt[p][i]);
      float o = y1[r] + ein[i] * y2[r] + Dh * xv;
      Y[((size_t)(b * SEQ) + c * 64 + i) * DINNER + h * HD + p] = f2bf(o);
    }
  }
}

// ---------------- y*silu(z), RMSNorm -> bf16 -------------------------------------
__global__ __launch_bounds__(256) void k_fuse(const unsigned short* __restrict__ Y,
    const unsigned short* __restrict__ ZX, const float* __restrict__ rw,
    unsigned short* __restrict__ YN)
{
  __shared__ float red[4];
  const int row = blockIdx.x, tid = threadIdx.x;
  const unsigned short* yr = Y + (size_t)row * DINNER;
  const unsigned short* zr = ZX + (size_t)row * DINPROJ;
  float v[6]; float s2 = 0.f;
  #pragma unroll
  for (int q = 0; q < 6; q++) {
    int col = q * 256 + tid;
    float z = bf2f(zr[col]);
    float yv = bf2f(yr[col]) * (z * sigm(z));
    v[q] = yv; s2 += yv * yv;
  }
  #pragma unroll
  for (int off = 32; off; off >>= 1) s2 += __shfl_down(s2, off);
  if ((tid & 63) == 0) red[tid >> 6] = s2;
  __syncthreads();
  const float rs = rsqrtf((red[0] + red[1] + red[2] + red[3]) * (1.f / DINNER) + EPSF);
  unsigned short* yo = YN + (size_t)row * DINNER;
  #pragma unroll
  for (int q = 0; q < 6; q++) {
    int col = q * 256 + tid;
    yo[col] = f2bf(v[q] * rs * rw[col]);
  }
}

// ---------------- launch ----------------------------------------------------------
extern "C" void kernel_launch(void* const* d_in, const int* in_sizes, int n_in,
                              void* d_out, int out_size, void* d_ws, size_t ws_size,
                              hipStream_t stream)
{
  const float* x         = (const float*)d_in[0];
  const float* ln_w      = (const float*)d_in[1];
  const float* ln_b      = (const float*)d_in[2];
  const float* in_proj_w = (const float*)d_in[3];
  const float* conv_w    = (const float*)d_in[4];
  const float* conv_b    = (const float*)d_in[5];
  const float* dt_bias   = (const float*)d_in[6];
  const float* A_log     = (const float*)d_in[7];
  const float* D_param   = (const float*)d_in[8];
  const float* rms_w     = (const float*)d_in[9];
  const float* out_proj_w= (const float*)d_in[10];
  const float* gate_w    = (const float*)d_in[11];
  const float* gate_b    = (const float*)d_in[12];
  const float* out_w     = (const float*)d_in[13];
  const float* out_b     = (const float*)d_in[14];
  float* out = (float*)d_out;
  char* ws = (char*)d_ws;

  // ---- workspace layout (bytes). peak = 177,848,320 B (~170 MB) ----
  const size_t WS_NEEDED = 177848320ull;
  if (ws_size < WS_NEEDED) return;

  unsigned short* XN    = (unsigned short*)(ws + 0);
  unsigned short* WIT   = (unsigned short*)(ws + 12582912);
  unsigned short* WGT   = (unsigned short*)(ws + 17534976);
  unsigned short* WOPT  = (unsigned short*)(ws + 18714624);
  unsigned short* WOT   = (unsigned short*)(ws + 21073920);
  unsigned short* ZXb   = (unsigned short*)(ws + 22253568);   // 8192x3224 bf16
  unsigned short* XBCCb = (unsigned short*)(ws + 75075584);   // 8192x1664 bf16
  unsigned short* Sb    = (unsigned short*)(ws + 102338560);  // 3072x4096 bf16 (25.2MB)
  unsigned short* Gb    = (unsigned short*)(ws + 127504384);  // 8192x768 bf16 (gate out)
  float*          CD    = (float*)(ws + 152670208);           // 3072 f32
  unsigned short* Yb    = (unsigned short*)(ws + 152682496);  // 8192x1536 bf16
  // overlays:
  unsigned short* YN    = (unsigned short*)(ws + 102338560);  // in dead-S region, ends at Gb
  unsigned short* YG    = (unsigned short*)(ws + 75075584);   // in XBCCb region (dead after chunkout)

  // 1) weight converts, single dispatch
  k_wtrans4<<<dim3(101, 48, 4), 256, 0, stream>>>(in_proj_w, WIT, gate_w, WGT,
                                                  out_proj_w, WOPT, out_w, WOT);
  // 2) layernorm
  k_ln<<<NTOK, 256, 0, stream>>>(x, ln_w, ln_b, XN);
  // 3) in_proj + gate GEMMs, one dispatch: 256^2 8-phase core (512 blocks, 1/CU, 2 rounds)
  k_ipg256<<<512, 512, 0, stream>>>(XN, WIT, ZXb, WGT, Gb, gate_b);
  // 4) LDS-tiled causal conv + silu (bf16 -> bf16)
  k_conv<<<dim3(13, 128), 256, 0, stream>>>(ZXb, conv_w, conv_b, XBCCb);
  // 5-7) SSD scan (S in bf16)
  k_chunkstate<<<dim3(NCHUNK, BSZ * NH), 256, 0, stream>>>(ZXb, XBCCb, dt_bias, A_log, Sb, CD);
  k_chunkrec<<<BSZ * NH * 16, 256, 0, stream>>>(Sb, CD);
  k_chunkout<<<dim3(NCHUNK, BSZ * NH), 256, 0, stream>>>(ZXb, XBCCb, Sb, dt_bias, A_log, D_param, Yb);
  // 8) y*silu(z) + RMSNorm -> bf16 (YN lands in dead-S region)
  k_fuse<<<NTOK, 256, 0, stream>>>(Yb, ZXb, rms_w, YN);
  // 9) out_proj GEMM with FUSED gate multiply (epi=3) -> YG (bf16); k_gatemul removed
  k_gemm<<<dim3(6, 64), 256, 0, stream>>>(YN, WOPT, nullptr, YG, NTOK, DMODEL, DINNER, 3,
                                          nullptr, nullptr, Gb);
  // 10) final GEMM + bias + residual -> d_out
  k_gemm<<<dim3(6, 64), 256, 0, stream>>>(YG, WOT, out, nullptr, NTOK, DMODEL, DMODEL, 2,
                                          out_b, x, nullptr);
}

// Round 2
// 352.014 us; speedup vs baseline: 1.0391x; 1.0042x over previous
//
#include <hip/hip_runtime.h>
#include <hip/hip_bf16.h>
#include <cstddef>

// ---------------- problem constants ----------------
#define DMODEL  768
#define DINNER  1536
#define DSTATE  64
#define NH      24
#define HD      64
#define CONVD   1664      // DINNER + 2*DSTATE
#define DINPROJ 3224      // 2*DINNER + 2*DSTATE + NH
#define SEQ     4096
#define BSZ     2
#define NTOK    8192      // BSZ*SEQ
#define NCHUNK  64        // SEQ/64
#define EPSF    1e-5f
#define LP      72        // LDS pitch (shorts) for SSD kernels
#define BUFS    8192      // 128*64 shorts per GEMM LDS buffer (128^2 core)

typedef __attribute__((ext_vector_type(8))) short  short8;
typedef __attribute__((ext_vector_type(4))) float  f32x4;

// ---------------- helpers ----------------
__device__ __forceinline__ unsigned short f2bf(float f) {
  union { float f; unsigned int u; } v; v.f = f;
  unsigned int r = v.u + 0x7fffu + ((v.u >> 16) & 1u);   // RNE
  return (unsigned short)(r >> 16);
}
__device__ __forceinline__ float bf2f(unsigned short u) {
  union { unsigned int i; float f; } v; v.i = ((unsigned int)u) << 16; return v.f;
}
__device__ __forceinline__ unsigned long long pack4bf(float a, float b, float c, float d) {
  return (unsigned long long)(f2bf(a) | ((unsigned int)f2bf(b) << 16))
       | ((unsigned long long)(f2bf(c) | ((unsigned int)f2bf(d) << 16)) << 32);
}
__device__ __forceinline__ float sigm(float x) { return 1.f / (1.f + __expf(-x)); }

// async 16B global -> LDS (lane i of the wave lands at ldsbase + i*16)
__device__ __forceinline__ void gld16(const unsigned short* g, unsigned short* l) {
  __builtin_amdgcn_global_load_lds(
      (const __attribute__((address_space(1))) unsigned int*)g,
      (__attribute__((address_space(3))) unsigned int*)l, 16, 0, 0);
}

// XCD-aware tile remap for 2D grids: XCD (id&7) owns a contiguous 1/8 of m-tiles.
__device__ __forceinline__ void xcd_tiles(int& m0, int& n0) {
  const int nt = gridDim.x, mt = gridDim.y;
  const int id = blockIdx.y * nt + blockIdx.x;
  const int mper = mt >> 3;
  const int xcd = id & 7, within = id >> 3;
  m0 = (xcd * mper + (within % mper)) * 128;
  n0 = (within / mper) * 128;
}

// ---------------- LayerNorm -> bf16 (also zeroes the ssq accumulator) -----------
__global__ __launch_bounds__(256) void k_ln(const float* __restrict__ x,
    const float* __restrict__ w, const float* __restrict__ b,
    unsigned short* __restrict__ xn, float* __restrict__ ssq)
{
  __shared__ float red[4];
  const int row = blockIdx.x, tid = threadIdx.x;
  if (blockIdx.x < 32) ssq[blockIdx.x * 256 + tid] = 0.f;   // 8192 f32 = 32x256
  const float* xr = x + (size_t)row * DMODEL;
  float v[3]; float s = 0.f;
  #pragma unroll
  for (int q = 0; q < 3; q++) { v[q] = xr[q*256 + tid]; s += v[q]; }
  #pragma unroll
  for (int off = 32; off; off >>= 1) s += __shfl_down(s, off);
  if ((tid & 63) == 0) red[tid >> 6] = s;
  __syncthreads();
  const float mu = (red[0] + red[1] + red[2] + red[3]) * (1.f / DMODEL);
  __syncthreads();
  float s2 = 0.f;
  #pragma unroll
  for (int q = 0; q < 3; q++) { float d = v[q] - mu; s2 += d * d; }
  #pragma unroll
  for (int off = 32; off; off >>= 1) s2 += __shfl_down(s2, off);
  if ((tid & 63) == 0) red[tid >> 6] = s2;
  __syncthreads();
  const float rs = rsqrtf((red[0] + red[1] + red[2] + red[3]) * (1.f / DMODEL) + EPSF);
  unsigned short* xo = xn + (size_t)row * DMODEL;
  #pragma unroll
  for (int q = 0; q < 3; q++) {
    int col = q*256 + tid;
    xo[col] = f2bf((v[q] - mu) * rs * w[col] + b[col]);
  }
}

// ---------------- 4 weight transposes in one dispatch (z-indexed) ----------------
// Case 2 (out_proj) folds rms_w into the weight: T2[n][k] = W[k][n] * rms_w[k].
__global__ __launch_bounds__(256) void k_wtrans4(
    const float* __restrict__ W0, unsigned short* __restrict__ T0,
    const float* __restrict__ W1, unsigned short* __restrict__ T1,
    const float* __restrict__ W2, unsigned short* __restrict__ T2,
    const float* __restrict__ W3, unsigned short* __restrict__ T3,
    const float* __restrict__ rmsw)
{
  const float* W; unsigned short* T; int K, N; const float* scale = nullptr;
  switch (blockIdx.z) {
    case 0:  W = W0; T = T0; K = 768;  N = 3224; break;
    case 1:  W = W1; T = T1; K = 768;  N = 768;  break;
    case 2:  W = W2; T = T2; K = 1536; N = 768;  scale = rmsw; break;
    default: W = W3; T = T3; K = 768;  N = 768;  break;
  }
  const int n0 = blockIdx.x * 32, k0 = blockIdx.y * 32;
  if (n0 >= N || k0 >= K) return;
  __shared__ float tile[32][33];
  const int tid = threadIdx.x;
  const int tx = tid & 31, ty = tid >> 5;           // 32 x 8
  #pragma unroll
  for (int r = 0; r < 4; r++) {
    int k = k0 + ty + 8*r;
    if (k < K && n0 + tx < N) tile[ty + 8*r][tx] = W[(size_t)k * N + n0 + tx];
  }
  __syncthreads();
  #pragma unroll
  for (int r = 0; r < 4; r++) {
    int n = n0 + ty + 8*r, k = k0 + tx;
    if (n < N && k < K) {
      float v = tile[tx][ty + 8*r];
      if (scale) v *= scale[k];
      T[(size_t)n * K + k] = f2bf(v);
    }
  }
}

// ======== 128x128 GEMM core, BK=64, DOUBLE-BUFFERED (1 barrier/iter) =============
// Prefetch distance 1; LDS swizzle: slot j of row r holds k-granule j ^ (r&7).
// epi: 0 plain, 1 sigmoid(C+bias[n]), 2 C+bias[n]+resid[m][n],
//      3 C*rsqrt(rsc[m]/DINNER+eps)*gmul[m][n].  Cb!=null -> bf16 out.
__device__ __forceinline__ void gemm_core(const unsigned short* __restrict__ A,
    const unsigned short* __restrict__ Bt, float* __restrict__ C,
    unsigned short* __restrict__ Cb,
    int M, int N, int K, int epi, const float* __restrict__ bias,
    const float* __restrict__ resid, const unsigned short* __restrict__ gmul,
    const float* __restrict__ rsc,
    int m0, int n0,
    unsigned short* As, unsigned short* Bs)      // each 2*BUFS shorts
{
  const int tid = threadIdx.x;
  const int lane = tid & 63, w = tid >> 6;
  const int wm = (w >> 1) * 64, wn = (w & 1) * 64;
  const int l15 = lane & 15, lq = lane >> 4;
  const int sw = l15 & 7;                  // fragment-read swizzle
  f32x4 acc[4][4];
  #pragma unroll
  for (int i = 0; i < 4; i++)
    #pragma unroll
    for (int j = 0; j < 4; j++) acc[i][j] = (f32x4){0.f, 0.f, 0.f, 0.f};

  int rowg[4], gq[4], nrg[4];
  #pragma unroll
  for (int r = 0; r < 4; r++) {
    int gi = (r * 4 + w) * 64 + lane;
    rowg[r] = gi >> 3;
    gq[r] = (gi & 7) ^ (rowg[r] & 7);
    int nr = n0 + rowg[r]; if (nr >= N) nr = N - 1;   // clamp; masked in epilogue
    nrg[r] = nr;
  }

  // prologue: loads(0) -> buffer 0
  #pragma unroll
  for (int r = 0; r < 4; r++)
    gld16(A + (size_t)(m0 + rowg[r]) * K + gq[r] * 8, &As[(r * 4 + w) * 512]);
  #pragma unroll
  for (int r = 0; r < 4; r++)
    gld16(Bt + (size_t)nrg[r] * K + gq[r] * 8, &Bs[(r * 4 + w) * 512]);

  int p = 0;
  for (int k0 = 0; k0 < K; k0 += 64) {
    __syncthreads();                       // drains loads(k0); protects buf 1-p
    if (k0 + 64 < K) {
      const int pn = p ^ 1;
      #pragma unroll
      for (int r = 0; r < 4; r++)
        gld16(A + (size_t)(m0 + rowg[r]) * K + (k0 + 64) + gq[r] * 8,
              &As[pn * BUFS + (r * 4 + w) * 512]);
      #pragma unroll
      for (int r = 0; r < 4; r++)
        gld16(Bt + (size_t)nrg[r] * K + (k0 + 64) + gq[r] * 8,
              &Bs[pn * BUFS + (r * 4 + w) * 512]);
    }
    const unsigned short* Ab = As + p * BUFS;
    const unsigned short* Bb = Bs + p * BUFS;
    #pragma unroll
    for (int ks = 0; ks < 2; ks++) {
      short8 a8[4], b8[4];
      #pragma unroll
      for (int mi = 0; mi < 4; mi++)
        a8[mi] = *(const short8*)(&Ab[(wm + 16 * mi + l15) * 64 + ((lq + 4 * ks) ^ sw) * 8]);
      #pragma unroll
      for (int ni = 0; ni < 4; ni++)
        b8[ni] = *(const short8*)(&Bb[(wn + 16 * ni + l15) * 64 + ((lq + 4 * ks) ^ sw) * 8]);
      #pragma unroll
      for (int mi = 0; mi < 4; mi++)
        #pragma unroll
        for (int ni = 0; ni < 4; ni++)
          acc[mi][ni] = __builtin_amdgcn_mfma_f32_16x16x32_bf16(a8[mi], b8[ni], acc[mi][ni], 0, 0, 0);
    }
    p ^= 1;
  }
  #pragma unroll
  for (int mi = 0; mi < 4; mi++) {
    #pragma unroll
    for (int r = 0; r < 4; r++) {
      int row = m0 + wm + 16*mi + lq*4 + r;
      float sc = (epi == 3) ? rsqrtf(rsc[row] * (1.f / DINNER) + EPSF) : 0.f;
      #pragma unroll
      for (int ni = 0; ni < 4; ni++) {
        int col = n0 + wn + 16*ni + l15;
        if (col < N) {
          float vv = acc[mi][ni][r];
          if (epi == 1)      vv = sigm(vv + bias[col]);
          else if (epi == 2) vv = vv + bias[col] + resid[(size_t)row * N + col];
          else if (epi == 3) vv = vv * sc * bf2f(gmul[(size_t)row * N + col]);
          if (Cb) Cb[(size_t)row * N + col] = f2bf(vv);
          else    C [(size_t)row * N + col] = vv;
        }
      }
    }
  }
}

__global__ __launch_bounds__(256) void k_gemm(const unsigned short* __restrict__ A,
    const unsigned short* __restrict__ Bt, float* __restrict__ C,
    unsigned short* __restrict__ Cb,
    int M, int N, int K, int epi, const float* __restrict__ bias,
    const float* __restrict__ resid, const unsigned short* __restrict__ gmul,
    const float* __restrict__ rsc)
{
  __shared__ alignas(16) unsigned short As[2 * BUFS];
  __shared__ alignas(16) unsigned short Bs[2 * BUFS];
  int m0, n0;
  xcd_tiles(m0, n0);
  gemm_core(A, Bt, C, Cb, M, N, K, epi, bias, resid, gmul, rsc, m0, n0, As, Bs);
}

// ================= 256x256 8-PHASE GEMM core (K=768 fixed) =======================
// 512 threads = 8 waves (2M x 4N). Per-wave C = 128x64 = acc[8][4] f32x4.
// LDS 128 KiB: A [2buf][256][64] bf16 (granule j of row r holds k-granule j^(r&7));
//              B [2buf][2ks][256][32] bf16 (granule j of row r holds j^((r>>1)&3)).
// MFMA operands SWAPPED: mfma(b,a) -> lane holds 4 consecutive COLUMNS -> 8B stores.
// Main loop j=0..4 (full prefetch), then PEELED TAIL (tiles 10/11, no prefetch,
// vmcnt(0) at tail-ph4) so vmcnt is CLEAN at function exit -> a second gemm256
// call in the same block can issue its prologue right after the epilogue stores
// (stores retire first in vmcnt order, then K0's 8 loads -> VW6 invariant holds).
template<int MIB>
__device__ __forceinline__ void mfma16(f32x4 (&acc)[8][4], const short8 (&a_)[4],
                                       const short8 (&bK)[4]) {
  __builtin_amdgcn_s_setprio(1);
  #pragma unroll
  for (int mi = 0; mi < 4; mi++)
    #pragma unroll
    for (int ni = 0; ni < 4; ni++)
      acc[MIB + mi][ni] =
          __builtin_amdgcn_mfma_f32_16x16x32_bf16(bK[ni], a_[mi], acc[MIB + mi][ni], 0, 0, 0);
  __builtin_amdgcn_s_setprio(0);
}

__device__ __forceinline__ short8 lds8(const unsigned short* L, int off) {
  return *(const short8*)(&L[off]);
}

#define FENCE() asm volatile("" ::: "memory")
#define BARX() do { __builtin_amdgcn_sched_barrier(0); FENCE(); \
  __builtin_amdgcn_s_barrier(); FENCE(); __builtin_amdgcn_sched_barrier(0); } while (0)
#define VW6() asm volatile("s_waitcnt vmcnt(6)" ::: "memory")

#define PH_LDA(BUF, MIBASE, AOFF) do { \
  a_[0] = lds8(L, (BUF) + arow + ((MIBASE)+0)*1024 + (AOFF)); \
  a_[1] = lds8(L, (BUF) + arow + ((MIBASE)+1)*1024 + (AOFF)); \
  a_[2] = lds8(L, (BUF) + arow + ((MIBASE)+2)*1024 + (AOFF)); \
  a_[3] = lds8(L, (BUF) + arow + ((MIBASE)+3)*1024 + (AOFF)); } while (0)

#define PH_LDB(BUF, KS) do { \
  bK[0] = lds8(L, brow + (BUF) + (KS)*8192 + 0*512 + boff); \
  bK[1] = lds8(L, brow + (BUF) + (KS)*8192 + 1*512 + boff); \
  bK[2] = lds8(L, brow + (BUF) + (KS)*8192 + 2*512 + boff); \
  bK[3] = lds8(L, brow + (BUF) + (KS)*8192 + 3*512 + boff); } while (0)

__device__ __forceinline__ void gemm256(const unsigned short* __restrict__ A,
    const unsigned short* __restrict__ Bt, unsigned short* __restrict__ Cb,
    int N, int m0, int n0, int epi, const float* __restrict__ bias,
    unsigned short* L)
{
  const int K = 768;                       // 12 K-tiles: j=0..4 full + peeled tail
  const int tid = threadIdx.x;
  const int lane = tid & 63, w = tid >> 6;
  const int wm2 = w >> 2, wn4 = w & 3;
  const int l15 = lane & 15, lq = lane >> 4;
  const int aoff0 = ((lq)     ^ (l15 & 7)) * 8;
  const int aoff1 = ((lq + 4) ^ (l15 & 7)) * 8;
  const int boff  = (lq ^ ((l15 >> 1) & 3)) * 8;
  const int arow = (wm2 * 128 + l15) * 64;                 // + (mi)*1024 + buf + aoff
  const int brow = 32768 + (wn4 * 64 + l15) * 32;          // + buf + ks*8192 + ni*512 + boff

  // staging sources (per-thread, constant)
  const int lr3 = lane >> 3, lr2 = lane >> 2;
  const int gqA = ((lane & 7) ^ lr3) * 8;
  const int gqB = ((lane & 3) ^ (lr3 & 3)) * 8;
  const unsigned short* sA0 = A + (size_t)(m0 + 8*w + lr3) * K + gqA;       // rows   8w..
  const unsigned short* sA1 = sA0 + (size_t)128 * K;                        // rows 128+8w
  const unsigned short* sA2 = sA0 + (size_t)64  * K;                        // rows  64+8w
  const unsigned short* sA3 = sA0 + (size_t)192 * K;                        // rows 192+8w
  int rb0 = n0 + 16*w + lr2;        if (rb0 > N - 1) rb0 = N - 1;
  int rb1 = n0 + 128 + 16*w + lr2;  if (rb1 > N - 1) rb1 = N - 1;
  const unsigned short* sB0 = Bt + (size_t)rb0 * K + gqB;
  const unsigned short* sB1 = Bt + (size_t)rb1 * K + gqB;

  // staging dests (shorts; + buf*16384, B also + ks*8192)
  const int dA0 = w*512, dA1 = (16+w)*512, dA2 = (8+w)*512, dA3 = (24+w)*512;
  const int dB0 = 32768 + w*512, dB1 = 32768 + (8+w)*512;

  f32x4 acc[8][4];
  #pragma unroll
  for (int i = 0; i < 8; i++)
    #pragma unroll
    for (int jj = 0; jj < 4; jj++) acc[i][jj] = (f32x4){0.f, 0.f, 0.f, 0.f};
  short8 bK[4];

  // ---- prologue: K0 full (8), then K1 {B-k0, A-X, B-k1} (6) ----
  gld16(sA0, &L[dA0]); gld16(sA1, &L[dA1]);                         // K0 A-X
  gld16(sA2, &L[dA2]); gld16(sA3, &L[dA3]);                         // K0 A-Y
  gld16(sB0, &L[dB0]); gld16(sB1, &L[dB1]);                         // K0 B-k0
  gld16(sB0 + 32, &L[dB0 + 8192]); gld16(sB1 + 32, &L[dB1 + 8192]); // K0 B-k1
  gld16(sB0 + 64, &L[dB0 + 16384]); gld16(sB1 + 64, &L[dB1 + 16384]);           // K1 B-k0
  gld16(sA0 + 64, &L[dA0 + 16384]); gld16(sA1 + 64, &L[dA1 + 16384]);           // K1 A-X
  gld16(sB0 + 96, &L[dB0 + 16384 + 8192]); gld16(sB1 + 96, &L[dB1 + 16384 + 8192]); // K1 B-k1
  VW6();                // retires preceding stores (if any) + K0's 8; K1's 6 in flight
  FENCE(); __builtin_amdgcn_s_barrier(); FENCE(); __builtin_amdgcn_sched_barrier(0);

  #pragma unroll 1
  for (int j = 0; j < 5; j++) {
    const int kO1 = (2*j + 1) * 64;
    const int kE  = (2*j + 2) * 64;
    const int kO3 = (2*j + 3) * 64;
    short8 a_[4];

    // phase 1: buf0, mi 0-3, ks0; load B-even-k0; stage A-odd-Y
    PH_LDA(0, 0, aoff0); PH_LDB(0, 0);
    gld16(sA2 + kO1, &L[dA2 + 16384]); gld16(sA3 + kO1, &L[dA3 + 16384]);
    BARX(); mfma16<0>(acc, a_, bK); BARX();
    // phase 2: buf0, mi 4-7, ks0; stage B-even'-k0
    PH_LDA(0, 4, aoff0);
    gld16(sB0 + kE, &L[dB0]); gld16(sB1 + kE, &L[dB1]);
    BARX(); mfma16<4>(acc, a_, bK); BARX();
    // phase 3: buf0, mi 0-3, ks1; load B-even-k1
    PH_LDA(0, 0, aoff1); PH_LDB(0, 1);
    BARX(); mfma16<0>(acc, a_, bK); BARX();
    // phase 4: buf0, mi 4-7, ks1; stage A-even'-X + B-even'-k1; WAIT
    PH_LDA(0, 4, aoff1);
    gld16(sA0 + kE, &L[dA0]); gld16(sA1 + kE, &L[dA1]);
    gld16(sB0 + kE + 32, &L[dB0 + 8192]); gld16(sB1 + kE + 32, &L[dB1 + 8192]);
    BARX(); mfma16<4>(acc, a_, bK);
    __builtin_amdgcn_sched_barrier(0); VW6(); BARX();
    // phase 5: buf1, mi 0-3, ks0; load B-odd-k0; stage A-even'-Y
    PH_LDA(16384, 0, aoff0); PH_LDB(16384, 0);
    gld16(sA2 + kE, &L[dA2]); gld16(sA3 + kE, &L[dA3]);
    BARX(); mfma16<0>(acc, a_, bK); BARX();
    // phase 6: buf1, mi 4-7, ks0; stage B-odd'-k0
    PH_LDA(16384, 4, aoff0);
    gld16(sB0 + kO3, &L[dB0 + 16384]); gld16(sB1 + kO3, &L[dB1 + 16384]);
    BARX(); mfma16<4>(acc, a_, bK); BARX();
    // phase 7: buf1, mi 0-3, ks1; load B-odd-k1
    PH_LDA(16384, 0, aoff1); PH_LDB(16384, 1);
    BARX(); mfma16<0>(acc, a_, bK); BARX();
    // phase 8: buf1, mi 4-7, ks1; stage A-odd'-X + B-odd'-k1; WAIT
    PH_LDA(16384, 4, aoff1);
    gld16(sA0 + kO3, &L[dA0 + 16384]); gld16(sA1 + kO3, &L[dA1 + 16384]);
    gld16(sB0 + kO3 + 32, &L[dB0 + 16384 + 8192]); gld16(sB1 + kO3 + 32, &L[dB1 + 16384 + 8192]);
    BARX(); mfma16<4>(acc, a_, bK);
    __builtin_amdgcn_sched_barrier(0); VW6(); BARX();
  }

  // ---- peeled tail: buf0 = tile 10, buf1 = tile 11; only stage 11.AY; drain ----
  {
    short8 a_[4];
    // ph1: stage A-11-Y (last read of buf1 A-Y was j=4 ph8, 1 phase ago -> safe)
    PH_LDA(0, 0, aoff0); PH_LDB(0, 0);
    gld16(sA2 + 704, &L[dA2 + 16384]); gld16(sA3 + 704, &L[dA3 + 16384]);
    BARX(); mfma16<0>(acc, a_, bK); BARX();
    PH_LDA(0, 4, aoff0);
    BARX(); mfma16<4>(acc, a_, bK); BARX();
    PH_LDA(0, 0, aoff1); PH_LDB(0, 1);
    BARX(); mfma16<0>(acc, a_, bK); BARX();
    // ph4: full drain -> tile 11 (incl. AY) all landed; vmcnt clean from here on
    PH_LDA(0, 4, aoff1);
    BARX(); mfma16<4>(acc, a_, bK);
    __builtin_amdgcn_sched_barrier(0);
    asm volatile("s_waitcnt vmcnt(0)" ::: "memory");
    BARX();
    // ph5-8: buf1 (tile 11), no stages, no waits
    PH_LDA(16384, 0, aoff0); PH_LDB(16384, 0);
    BARX(); mfma16<0>(acc, a_, bK); BARX();
    PH_LDA(16384, 4, aoff0);
    BARX(); mfma16<4>(acc, a_, bK); BARX();
    PH_LDA(16384, 0, aoff1); PH_LDB(16384, 1);
    BARX(); mfma16<0>(acc, a_, bK); BARX();
    PH_LDA(16384, 4, aoff1);
    BARX(); mfma16<4>(acc, a_, bK); BARX();
  }

  // ---- epilogue: lane holds cols (ncb+16ni .. +3) of row (mrow+16mi) ----
  const int mrow = m0 + wm2 * 128 + l15;
  const int ncb  = n0 + wn4 * 64 + 4 * lq;
  if (epi == 0) {
    #pragma unroll
    for (int mi = 0; mi < 8; mi++) {
      unsigned short* Crow = Cb + (size_t)(mrow + 16*mi) * N + ncb;
      #pragma unroll
      for (int ni = 0; ni < 4; ni++) {
        if (ncb + 16*ni < N) {
          f32x4 v = acc[mi][ni];
          *(unsigned long long*)(Crow + 16*ni) = pack4bf(v[0], v[1], v[2], v[3]);
        }
      }
    }
  } else {            // epi==1: sigmoid(C + bias[n]) (N=768, no masking needed)
    f32x4 bb[4];
    #pragma unroll
    for (int ni = 0; ni < 4; ni++) bb[ni] = *(const f32x4*)(bias + ncb + 16*ni);
    #pragma unroll
    for (int mi = 0; mi < 8; mi++) {
      unsigned short* Crow = Cb + (size_t)(mrow + 16*mi) * N + ncb;
      #pragma unroll
      for (int ni = 0; ni < 4; ni++) {
        f32x4 v = acc[mi][ni];
        *(unsigned long long*)(Crow + 16*ni) = pack4bf(
            sigm(v[0] + bb[ni][0]), sigm(v[1] + bb[ni][1]),
            sigm(v[2] + bb[ni][2]), sigm(v[3] + bb[ni][3]));
      }
    }
  }
}

// in_proj (13n x 32m tiles) + gate (3n x 32m) as 512 tiles over 256 PERSISTENT
// blocks (2 tiles each, same XCD, SAME A-panel pair -> tile2 prologue L2-hot and
// overlapped with tile1 epilogue stores). Single occupancy round, no ramp.
__global__ __launch_bounds__(512, 2) void k_ipg256(
    const unsigned short* __restrict__ XN, const unsigned short* __restrict__ WIT,
    unsigned short* __restrict__ ZXb,
    const unsigned short* __restrict__ WGT, unsigned short* __restrict__ Gb,
    const float* __restrict__ gate_b)
{
  __shared__ alignas(16) unsigned short L[65536];   // 128 KiB
  const int bid = blockIdx.x;
  const int xcd = bid & 7;
  #pragma unroll 1
  for (int t = 0; t < 2; t++) {
    const int within = (bid >> 3) + 32 * t;
    const unsigned short* Btp; unsigned short* Cbp;
    int N_, m0, n0, epi; const float* bias;
    if (within < 52) {
      Btp = WIT; Cbp = ZXb; N_ = DINPROJ; epi = 0; bias = nullptr;
      m0 = (xcd * 4 + (within & 3)) * 256;
      n0 = (within >> 2) * 256;
    } else {
      const int w2 = within - 52;
      Btp = WGT; Cbp = Gb; N_ = DMODEL; epi = 1; bias = gate_b;
      m0 = (xcd * 4 + (w2 & 3)) * 256;
      n0 = (w2 >> 2) * 256;
    }
    gemm256(XN, Btp, Cbp, N_, m0, n0, epi, bias, L);
  }
}

// ---------------- LDS-tiled causal conv1d (K=4) + SiLU ---------------------------
__global__ __launch_bounds__(256) void k_conv(const unsigned short* __restrict__ zx,
    const float* __restrict__ cw, const float* __restrict__ cb,
    unsigned short* __restrict__ out)
{
  __shared__ alignas(8) unsigned short tile[67][132];   // pitch 264 B
  const int tid = threadIdx.x;
  const int c0 = blockIdx.x * 128;          // 13 tiles x 128 = 1664 = CONVD
  const int tc = blockIdx.y;                // 128 token-chunks of 64
  const int t0 = tc * 64;
  const bool haloOK = (tc & 63) != 0;       // chunk 0 of each batch has no halo
  for (int i = tid; i < 67 * 16; i += 256) {
    int row = i >> 4, g = i & 15;
    unsigned long long v0 = 0, v1 = 0;
    if (row >= 3 || haloOK) {
      const unsigned short* p = zx + (size_t)(t0 - 3 + row) * DINPROJ + DINNER + c0 + g * 8;
      v0 = *(const unsigned long long*)p;
      v1 = *(const unsigned long long*)(p + 4);
    }
    *(unsigned long long*)(&tile[row][g * 8])     = v0;
    *(unsigned long long*)(&tile[row][g * 8 + 4]) = v1;
  }
  __syncthreads();
  const int ch0 = (tid & 63) * 2;           // 0..126
  const int trow = tid >> 6;                // 0..3
  const int cg = c0 + ch0;
  float cw0[4], cw1[4];
  #pragma unroll
  for (int k = 0; k < 4; k++) { cw0[k] = cw[cg * 4 + k]; cw1[k] = cw[(cg + 1) * 4 + k]; }
  const float cb0 = cb[cg], cb1 = cb[cg + 1];
  #pragma unroll
  for (int q = 0; q < 16; q++) {
    int tq = trow * 16 + q;
    float a0 = cb0, a1 = cb1;
    #pragma unroll
    for (int k = 0; k < 4; k++) {
      unsigned int u = *(const unsigned int*)(&tile[tq + k][ch0]);
      a0 += bf2f((unsigned short)u) * cw0[k];
      a1 += bf2f((unsigned short)(u >> 16)) * cw1[k];
    }
    float s0 = a0 * sigm(a0), s1 = a1 * sigm(a1);
    *(unsigned int*)(out + (size_t)(t0 + tq) * CONVD + cg) =
        (unsigned int)f2bf(s0) | ((unsigned int)f2bf(s1) << 16);
  }
}

// ---------------- SSD pass 1 (MFMA): S[bh,c][n][p] (bf16) ------------------------
__global__ __launch_bounds__(256) void k_chunkstate(const unsigned short* __restrict__ zx,
    const unsigned short* __restrict__ xbcc, const float* __restrict__ dt_bias,
    const float* __restrict__ A_log, unsigned short* __restrict__ S, float* __restrict__ CD)
{
  const int c = blockIdx.x, bh = blockIdx.y;
  const int b = bh / NH, h = bh % NH;
  const int tid = threadIdx.x;
  const int lane = tid & 63, w = tid >> 6;
  const int l15 = lane & 15, lq = lane >> 4;
  __shared__ float wv_[64];
  __shared__ alignas(16) unsigned short Bwt[64][LP];  // [n][s]
  __shared__ alignas(16) unsigned short Xt [64][LP];  // [p][s]

  if (tid < 64) {                     // wave 0: dt, prefix-scan of Lc
    int t = c * 64 + tid;
    float xx = bf2f(zx[((size_t)(b * SEQ + t)) * DINPROJ + (DINNER + CONVD) + h]) + dt_bias[h];
    float dt_ = (xx > 15.f) ? xx : log1pf(__expf(xx));
    float Ah = -__expf(A_log[h]);
    float v = dt_ * Ah;
    #pragma unroll
    for (int off = 1; off < 64; off <<= 1) {
      float u = __shfl_up(v, off);
      if (tid >= off) v += u;
    }
    float L63 = __shfl(v, 63);
    wv_[tid] = __expf(L63 - v) * dt_;
    if (tid == 63) CD[bh * 64 + c] = __expf(v);
  }
  unsigned long long braw[4];
  #pragma unroll
  for (int it = 0; it < 4; it++) {
    int i4 = tid + 256 * it;
    int s = i4 >> 4, q4 = (i4 & 15) * 4;
    size_t rb = ((size_t)(b * SEQ) + c * 64 + s) * CONVD;
    braw[it] = *(const unsigned long long*)(xbcc + rb + DINNER + q4);
    unsigned short xs[4];
    *(unsigned long long*)xs = *(const unsigned long long*)(xbcc + rb + h * HD + q4);
    Xt[q4+0][s] = xs[0]; Xt[q4+1][s] = xs[1]; Xt[q4+2][s] = xs[2]; Xt[q4+3][s] = xs[3];
  }
  __syncthreads();
  #pragma unroll
  for (int it = 0; it < 4; it++) {
    int i4 = tid + 256 * it;
    int s = i4 >> 4, q4 = (i4 & 15) * 4;
    float wsc = wv_[s];
    unsigned short us[4];
    *(unsigned long long*)us = braw[it];
    Bwt[q4+0][s] = f2bf(bf2f(us[0]) * wsc);
    Bwt[q4+1][s] = f2bf(bf2f(us[1]) * wsc);
    Bwt[q4+2][s] = f2bf(bf2f(us[2]) * wsc);
    Bwt[q4+3][s] = f2bf(bf2f(us[3]) * wsc);
  }
  __syncthreads();
  const int n0 = 16 * w;
  short8 a0 = *(const short8*)(&Bwt[n0 + l15][lq * 8]);
  short8 a1 = *(const short8*)(&Bwt[n0 + l15][32 + lq * 8]);
  size_t sb = ((size_t)bh * 64 + c) * 4096;
  #pragma unroll
  for (int pt = 0; pt < 4; pt++) {
    f32x4 acc = (f32x4){0.f, 0.f, 0.f, 0.f};
    short8 b0 = *(const short8*)(&Xt[16*pt + l15][lq * 8]);
    short8 b1 = *(const short8*)(&Xt[16*pt + l15][32 + lq * 8]);
    acc = __builtin_amdgcn_mfma_f32_16x16x32_bf16(a0, b0, acc, 0, 0, 0);
    acc = __builtin_amdgcn_mfma_f32_16x16x32_bf16(a1, b1, acc, 0, 0, 0);
    #pragma unroll
    for (int r = 0; r < 4; r++) {
      int n = n0 + 4*lq + r, p = 16*pt + l15;
      S[sb + (size_t)n * 64 + p] = f2bf(acc[r]);
    }
  }
}

// ---------------- SSD pass 2: chunk recurrence (batched-prefetch loads) ----------
__global__ __launch_bounds__(256) void k_chunkrec(unsigned short* __restrict__ S,
    const float* __restrict__ CD)
{
  const int bh = blockIdx.x >> 4, part = blockIdx.x & 15;
  const int e = part * 256 + threadIdx.x;
  float g = 0.f;
  size_t base = (size_t)bh * 64 * 4096 + e;
  const float* cdp = CD + bh * 64;
  #pragma unroll 1
  for (int cb = 0; cb < 64; cb += 8) {
    unsigned short sv[8];
    #pragma unroll
    for (int u = 0; u < 8; u++) sv[u] = S[base + (size_t)(cb + u) * 4096];
    #pragma unroll
    for (int u = 0; u < 8; u++) {
      float s = bf2f(sv[u]);
      S[base + (size_t)(cb + u) * 4096] = f2bf(g);   // slot c now holds G_c
      g = cdp[cb + u] * g + s;
    }
  }
}

// ---------------- SSD pass 3 (MFMA): y*silu(z) fused, per-row ssq atomics --------
__global__ __launch_bounds__(256) void k_chunkout(const unsigned short* __restrict__ zx,
    const unsigned short* __restrict__ xbcc, const unsigned short* __restrict__ S,
    const float* __restrict__ dt_bias, const float* __restrict__ A_log,
    const float* __restrict__ Dp, unsigned short* __restrict__ Y,
    float* __restrict__ ssq)
{
  const int c = blockIdx.x, bh = blockIdx.y;
  const int b = bh / NH, h = bh % NH;
  const int tid = threadIdx.x;
  const int lane = tid & 63, w = tid >> 6;
  const int l15 = lane & 15, lq = lane >> 4;
  __shared__ float dts[64], Lc[64], ein[64];
  __shared__ alignas(16) unsigned short Cs  [64][LP];  // [i][n]
  __shared__ alignas(16) unsigned short BsPs[64][LP];  // [s][n], then P[i][s]
  __shared__ alignas(16) unsigned short Xt  [64][LP];  // [p][s]
  __shared__ alignas(16) unsigned short Gt  [64][LP];  // [p][n]

  if (tid < 64) {                     // wave 0: dt, prefix-scan of Lc
    int t = c * 64 + tid;
    float xx = bf2f(zx[((size_t)(b * SEQ + t)) * DINPROJ + (DINNER + CONVD) + h]) + dt_bias[h];
    float dt_ = (xx > 15.f) ? xx : log1pf(__expf(xx));
    dts[tid] = dt_;
    float Ah = -__expf(A_log[h]);
    float v = dt_ * Ah;
    #pragma unroll
    for (int off = 1; off < 64; off <<= 1) {
      float u = __shfl_up(v, off);
      if (tid >= off) v += u;
    }
    Lc[tid] = v;
    ein[tid] = __expf(v);
  }
  const size_t gslot = ((size_t)bh * 64 + c) * 4096;
  #pragma unroll
  for (int it = 0; it < 4; it++) {
    int i4 = tid + 256 * it;
    int rr = i4 >> 4, q4 = (i4 & 15) * 4;
    size_t rb = ((size_t)(b * SEQ) + c * 64 + rr) * CONVD;
    const unsigned short* pC = xbcc + rb + (DINNER + DSTATE) + q4;
    Cs[rr][q4+0] = pC[0]; Cs[rr][q4+1] = pC[1]; Cs[rr][q4+2] = pC[2]; Cs[rr][q4+3] = pC[3];
    const unsigned short* pB = xbcc + rb + DINNER + q4;
    BsPs[rr][q4+0] = pB[0]; BsPs[rr][q4+1] = pB[1]; BsPs[rr][q4+2] = pB[2]; BsPs[rr][q4+3] = pB[3];
    unsigned short xs[4];
    *(unsigned long long*)xs = *(const unsigned long long*)(xbcc + rb + h * HD + q4);
    Xt[q4+0][rr] = xs[0]; Xt[q4+1][rr] = xs[1]; Xt[q4+2][rr] = xs[2]; Xt[q4+3][rr] = xs[3];
    unsigned short gs[4];
    *(unsigned long long*)gs = *(const unsigned long long*)(S + gslot + (size_t)i4 * 4);
    Gt[q4+0][rr] = gs[0]; Gt[q4+1][rr] = gs[1]; Gt[q4+2][rr] = gs[2]; Gt[q4+3][rr] = gs[3];
  }
  __syncthreads();
  // ---- matmul1: G[i][s] = sum_n C[i][n] B[s][n]; apply causal decay mask -> P ----
  const int i0 = 16 * w;
  short8 ac0 = *(const short8*)(&Cs[i0 + l15][lq * 8]);
  short8 ac1 = *(const short8*)(&Cs[i0 + l15][32 + lq * 8]);
  float pp[4][4];
  #pragma unroll
  for (int st = 0; st < 4; st++) {
    f32x4 g = (f32x4){0.f, 0.f, 0.f, 0.f};
    if (st <= w) {                                   // wave-uniform causal skip
      short8 b0 = *(const short8*)(&BsPs[16*st + l15][lq * 8]);
      short8 b1 = *(const short8*)(&BsPs[16*st + l15][32 + lq * 8]);
      g = __builtin_amdgcn_mfma_f32_16x16x32_bf16(ac0, b0, g, 0, 0, 0);
      g = __builtin_amdgcn_mfma_f32_16x16x32_bf16(ac1, b1, g, 0, 0, 0);
    }
    #pragma unroll
    for (int r = 0; r < 4; r++) {
      int i = i0 + 4*lq + r, s = 16*st + l15;
      pp[st][r] = (s <= i) ? g[r] * __expf(Lc[i] - Lc[s]) * dts[s] : 0.f;
    }
  }
  __syncthreads();                                   // all waves done reading Bs
  #pragma unroll
  for (int st = 0; st < 4; st++)
    #pragma unroll
    for (int r = 0; r < 4; r++)
      BsPs[i0 + 4*lq + r][16*st + l15] = f2bf(pp[st][r]);   // P[i][s], s contiguous
  __syncthreads();
  // ---- matmul2+3: Y[i][p] = (P@X + ein[i]*(C@G) + D*x) * silu(z) ----
  short8 ap0 = *(const short8*)(&BsPs[i0 + l15][lq * 8]);
  short8 ap1 = *(const short8*)(&BsPs[i0 + l15][32 + lq * 8]);
  const float Dh = Dp[h];
  float sq[4] = {0.f, 0.f, 0.f, 0.f};
  #pragma unroll
  for (int pt = 0; pt < 4; pt++) {
    const int p0 = 16 * pt;
    f32x4 y1 = (f32x4){0.f, 0.f, 0.f, 0.f};
    f32x4 y2 = (f32x4){0.f, 0.f, 0.f, 0.f};
    short8 bx0 = *(const short8*)(&Xt[p0 + l15][lq * 8]);
    y1 = __builtin_amdgcn_mfma_f32_16x16x32_bf16(ap0, bx0, y1, 0, 0, 0);
    if (w >= 2) {                                    // P rows of wave w have k < 16(w+1)
      short8 bx1 = *(const short8*)(&Xt[p0 + l15][32 + lq * 8]);
      y1 = __builtin_amdgcn_mfma_f32_16x16x32_bf16(ap1, bx1, y1, 0, 0, 0);
    }
    short8 bg0 = *(const short8*)(&Gt[p0 + l15][lq * 8]);
    short8 bg1 = *(const short8*)(&Gt[p0 + l15][32 + lq * 8]);
    y2 = __builtin_amdgcn_mfma_f32_16x16x32_bf16(ac0, bg0, y2, 0, 0, 0);
    y2 = __builtin_amdgcn_mfma_f32_16x16x32_bf16(ac1, bg1, y2, 0, 0, 0);
    #pragma unroll
    for (int r = 0; r < 4; r++) {
      int i = i0 + 4*lq + r, p = p0 + l15;
      float xv = bf2f(Xt[p][i]);
      float o = y1[r] + ein[i] * y2[r] + Dh * xv;
      size_t row = (size_t)(b * SEQ) + c * 64 + i;
      float zv = bf2f(zx[row * DINPROJ + h * HD + p]);
      float og = o * (zv * sigm(zv));
      Y[row * DINNER + h * HD + p] = f2bf(og);
      sq[r] += og * og;
    }
  }
  // per-row sum of squares: reduce over the 16 l15 lanes (same lq), 1 atomic/row
  #pragma unroll
  for (int r = 0; r < 4; r++) {
    float s = sq[r];
    s += __shfl_xor(s, 1); s += __shfl_xor(s, 2);
    s += __shfl_xor(s, 4); s += __shfl_xor(s, 8);
    if (l15 == 0)
      atomicAdd(ssq + (size_t)(b * SEQ) + c * 64 + (i0 + 4*lq + r), s);
  }
}

// ---------------- launch ----------------------------------------------------------
extern "C" void kernel_launch(void* const* d_in, const int* in_sizes, int n_in,
                              void* d_out, int out_size, void* d_ws, size_t ws_size,
                              hipStream_t stream)
{
  const float* x         = (const float*)d_in[0];
  const float* ln_w      = (const float*)d_in[1];
  const float* ln_b      = (const float*)d_in[2];
  const float* in_proj_w = (const float*)d_in[3];
  const float* conv_w    = (const float*)d_in[4];
  const float* conv_b    = (const float*)d_in[5];
  const float* dt_bias   = (const float*)d_in[6];
  const float* A_log     = (const float*)d_in[7];
  const float* D_param   = (const float*)d_in[8];
  const float* rms_w     = (const float*)d_in[9];
  const float* out_proj_w= (const float*)d_in[10];
  const float* gate_w    = (const float*)d_in[11];
  const float* gate_b    = (const float*)d_in[12];
  const float* out_w     = (const float*)d_in[13];
  const float* out_b     = (const float*)d_in[14];
  float* out = (float*)d_out;
  char* ws = (char*)d_ws;

  // ---- workspace layout (bytes). peak = 177,848,320 B (~170 MB) ----
  // k_fuse removed: YN gone; ssq (8192 f32) lives after Gb (ends 140087296).
  const size_t WS_NEEDED = 177848320ull;
  if (ws_size < WS_NEEDED) return;

  unsigned short* XN    = (unsigned short*)(ws + 0);
  unsigned short* WIT   = (unsigned short*)(ws + 12582912);
  unsigned short* WGT   = (unsigned short*)(ws + 17534976);
  unsigned short* WOPT  = (unsigned short*)(ws + 18714624);
  unsigned short* WOT   = (unsigned short*)(ws + 21073920);
  unsigned short* ZXb   = (unsigned short*)(ws + 22253568);   // 8192x3224 bf16
  unsigned short* XBCCb = (unsigned short*)(ws + 75075584);   // 8192x1664 bf16
  unsigned short* Sb    = (unsigned short*)(ws + 102338560);  // 3072x4096 bf16 (25.2MB)
  unsigned short* Gb    = (unsigned short*)(ws + 127504384);  // 8192x768 bf16 (gate out)
  float*          ssq   = (float*)(ws + 140087296);           // 8192 f32 row sum-sq
  float*          CD    = (float*)(ws + 152670208);           // 3072 f32
  unsigned short* Yb    = (unsigned short*)(ws + 152682496);  // 8192x1536 bf16 (y*silu(z))
  // overlay:
  unsigned short* YG    = (unsigned short*)(ws + 75075584);   // in XBCCb region (dead after chunkout)

  // 1) weight converts (rms_w folded into WOPT), single dispatch
  k_wtrans4<<<dim3(101, 48, 4), 256, 0, stream>>>(in_proj_w, WIT, gate_w, WGT,
                                                  out_proj_w, WOPT, out_w, WOT, rms_w);
  // 2) layernorm (+ ssq zero-init)
  k_ln<<<NTOK, 256, 0, stream>>>(x, ln_w, ln_b, XN, ssq);
  // 3) in_proj + gate GEMMs: persistent 256^2 8-phase core, 256 blocks x 2 tiles
  k_ipg256<<<256, 512, 0, stream>>>(XN, WIT, ZXb, WGT, Gb, gate_b);
  // 4) LDS-tiled causal conv + silu (bf16 -> bf16)
  k_conv<<<dim3(13, 128), 256, 0, stream>>>(ZXb, conv_w, conv_b, XBCCb);
  // 5-7) SSD scan (S in bf16); chunkout fuses y*silu(z) + ssq accumulation
  k_chunkstate<<<dim3(NCHUNK, BSZ * NH), 256, 0, stream>>>(ZXb, XBCCb, dt_bias, A_log, Sb, CD);
  k_chunkrec<<<BSZ * NH * 16, 256, 0, stream>>>(Sb, CD);
  k_chunkout<<<dim3(NCHUNK, BSZ * NH), 256, 0, stream>>>(ZXb, XBCCb, Sb, dt_bias, A_log,
                                                         D_param, Yb, ssq);
  // 8) out_proj GEMM: A = y*silu(z); epilogue applies rsqrt(ssq/1536+eps) (RMS) * gate
  k_gemm<<<dim3(6, 64), 256, 0, stream>>>(Yb, WOPT, nullptr, YG, NTOK, DMODEL, DINNER, 3,
                                          nullptr, nullptr, Gb, ssq);
  // 9) final GEMM + bias + residual -> d_out
  k_gemm<<<dim3(6, 64), 256, 0, stream>>>(YG, WOT, out, nullptr, NTOK, DMODEL, DMODEL, 2,
                                          out_b, x, nullptr, nullptr);
}